// Round 10
// baseline (194.840 us; speedup 1.0000x reference)
//
#include <hip/hip_runtime.h>
#include <hip/hip_bf16.h>

#define N_NODES 10000
#define IN_DIM 256
#define HID 512      // HEADS*HIDDEN
#define HEADS 8
#define OUT_DIM 256
#define NEG 0.2f
#define CAP 128      // bucket capacity per node (actual max deg ~57 incl self-loop)
#define WPREP_BLOCKS (((IN_DIM*HID)+(HID*OUT_DIM))/256)   // 1024

typedef __hip_bfloat16 bf16;
typedef __attribute__((ext_vector_type(8))) short short8;
typedef __attribute__((ext_vector_type(4))) float f32x4;

__device__ __forceinline__ float ldm(const void* p, long i, int mode){
  if(mode) return ((const float*)p)[i];
  return __bfloat162float(((const bf16*)p)[i]);
}
__device__ __forceinline__ unsigned short f2bf(float f){
  bf16 b = __float2bfloat16(f);
  return *(unsigned short*)&b;
}
__device__ __forceinline__ float bflo(unsigned int u){ return __uint_as_float(u<<16); }
__device__ __forceinline__ float bfhi(unsigned int u){ return __uint_as_float(u&0xffff0000u); }

// block 0: sniff bf16-vs-f32. blocks 1..: zero cnt (el1/er1 direct-stored by
// gemm1 epilogue; el2/er2 are per-tile partials, also direct-stored).
__global__ void detect_zero_k(const unsigned short* w1raw, int* mode, int* cnt){
  int t = threadIdx.x;
  if(blockIdx.x==0){
    __shared__ int sbad;
    if(t==0) sbad=0;
    __syncthreads();
    int bad=0;
    for(int i=t;i<512;i+=256){
      unsigned int u = ((unsigned int)w1raw[i])<<16;
      float f = __uint_as_float(u);
      if(!(f==f) || fabsf(f) > 100.0f) bad++;
    }
    #pragma unroll
    for(int o=32;o>0;o>>=1) bad += __shfl_down(bad,o);
    if((t&63)==0) atomicAdd(&sbad, bad);
    __syncthreads();
    if(t==0) *mode = (sbad>10) ? 1 : 0;
  } else {
    int i = (blockIdx.x-1)*256 + t;
    if(i<N_NODES) cnt[i]=0;
  }
}

// blocks [0,WPREP_BLOCKS): weight transpose W1->wt1[HID][K1], W2->wt2[OUT][K2].
// blocks [WPREP_BLOCKS,..): bucketed CSR scatter (cnt pre-zeroed).
__global__ void prep2_k(const void* W1, const void* W2, unsigned short* wt1,
                        unsigned short* wt2, const int* modep,
                        const int* src, const int* dst, int* cnt, int* bucket, int E){
  int b = blockIdx.x, t = threadIdx.x;
  if(b < WPREP_BLOCKS){
    int md = *modep;
    long i = (long)b*256 + t;
    const long n1 = (long)IN_DIM*HID;
    if(i < n1){
      int k = (int)(i/HID), n = (int)(i%HID);
      unsigned short v = md ? f2bf(((const float*)W1)[i]) : ((const unsigned short*)W1)[i];
      wt1[(long)n*IN_DIM + k] = v;
    } else {
      long j = i - n1;
      int k = (int)(j/OUT_DIM), n = (int)(j%OUT_DIM);
      unsigned short v = md ? f2bf(((const float*)W2)[j]) : ((const unsigned short*)W2)[j];
      wt2[(long)n*HID + k] = v;
    }
  } else {
    int e = (b-WPREP_BLOCKS)*256 + t;
    if(e<E){
      int d = dst[e];
      int pos = atomicAdd(&cnt[d], 1);
      if(pos < CAP) bucket[(long)d*CAP + pos] = src[e];
    }
  }
}

// C[M,N]bf16 = A[M,K] @ Bt[N,K]^T with fused attention-dot epilogue.
// 64x64 tile, BK=32, 4 waves (each 32x32 = 2x2 16x16x32 frags).
// dmode==1: el/er direct-STORE at stride 8 (head=bx is sole contributor).
// dmode==2: el/er direct-STORE per-tile partials elp[bx*N_NODES+row].
__global__ __launch_bounds__(256) void gemm_k(const void* A, const unsigned short* Bt,
                                              unsigned short* C, int M, int N, int K,
                                              int asel, const int* modep,
                                              const void* al, const void* ar,
                                              float* el, float* er, int dmode){
  int md = *modep;
  int am = asel ? md : 0;   // 1 -> A is f32
  __shared__ short As[64*40];
  __shared__ short Bs[64*40];
  __shared__ float led[64], ler[64];
  int t = threadIdx.x;
  int lane = t & 63, wave = t >> 6;
  int l15 = lane & 15, quad = lane >> 4;
  int wm = (wave>>1)*32, wn = (wave&1)*32;
  int mbase = blockIdx.y*64, nbase = blockIdx.x*64;

  f32x4 acc[2][2];
  #pragma unroll
  for(int i=0;i<2;i++)
    #pragma unroll
    for(int j=0;j<2;j++) acc[i][j] = (f32x4){0.f,0.f,0.f,0.f};

  int row = t>>2, kk = (t&3)*8;
  long arow = (long)(mbase+row)*K, brow = (long)(nbase+row)*K;
  bool av = (mbase+row) < M;
  const unsigned short* Ab = (const unsigned short*)A;
  const float* Af = (const float*)A;

  for(int k0=0;k0<K;k0+=32){
    short8 a = (short8){0,0,0,0,0,0,0,0};
    if(am){
      if(av){
        float4 x = *(const float4*)(Af + arow + k0 + kk);
        float4 y = *(const float4*)(Af + arow + k0 + kk + 4);
        a[0]=f2bf(x.x); a[1]=f2bf(x.y); a[2]=f2bf(x.z); a[3]=f2bf(x.w);
        a[4]=f2bf(y.x); a[5]=f2bf(y.y); a[6]=f2bf(y.z); a[7]=f2bf(y.w);
      }
    } else {
      if(av) a = *(const short8*)(Ab + arow + k0 + kk);
    }
    short8 b = *(const short8*)(Bt + brow + k0 + kk);
    __syncthreads();
    *(short8*)(As + row*40 + kk) = a;
    *(short8*)(Bs + row*40 + kk) = b;
    __syncthreads();
    short8 af[2], bfr[2];
    #pragma unroll
    for(int mi=0;mi<2;mi++) af[mi]  = *(short8*)(As + (wm + mi*16 + l15)*40 + quad*8);
    #pragma unroll
    for(int ni=0;ni<2;ni++) bfr[ni] = *(short8*)(Bs + (wn + ni*16 + l15)*40 + quad*8);
    #pragma unroll
    for(int mi=0;mi<2;mi++)
      #pragma unroll
      for(int ni=0;ni<2;ni++)
        acc[mi][ni] = __builtin_amdgcn_mfma_f32_16x16x32_bf16(af[mi], bfr[ni], acc[mi][ni], 0,0,0);
  }

  // C store (bf16)
  #pragma unroll
  for(int mi=0;mi<2;mi++){
    #pragma unroll
    for(int ni=0;ni<2;ni++){
      int grow0 = mbase + wm + mi*16 + quad*4;
      int gcol  = nbase + wn + ni*16 + l15;
      #pragma unroll
      for(int r=0;r<4;r++){
        int grow = grow0 + r;
        if(grow < M) C[(long)grow*N + gcol] = f2bf(acc[mi][ni][r]);
      }
    }
  }

  // fused dots epilogue: partial el/er for this block's 64 rows
  float avv[2], rvv[2];
  #pragma unroll
  for(int ni=0;ni<2;ni++){
    int gc = nbase + wn + ni*16 + l15;
    avv[ni] = ldm(al, gc, md);
    rvv[ni] = ldm(ar, gc, md);
  }
  __syncthreads();
  if(t<64){ led[t]=0.f; ler[t]=0.f; }
  __syncthreads();
  #pragma unroll
  for(int mi=0;mi<2;mi++){
    #pragma unroll
    for(int r=0;r<4;r++){
      float pl = acc[mi][0][r]*avv[0] + acc[mi][1][r]*avv[1];
      float pr = acc[mi][0][r]*rvv[0] + acc[mi][1][r]*rvv[1];
      #pragma unroll
      for(int o=1;o<16;o<<=1){ pl += __shfl_xor(pl,o); pr += __shfl_xor(pr,o); }
      if(l15==0){
        int lr = wm + mi*16 + quad*4 + r;
        atomicAdd(&led[lr], pl);
        atomicAdd(&ler[lr], pr);
      }
    }
  }
  __syncthreads();
  if(t<64){
    int grow = mbase + t;
    if(grow < M){
      if(dmode==1){
        el[(long)grow*HEADS + blockIdx.x] = led[t];
        er[(long)grow*HEADS + blockIdx.x] = ler[t];
      } else {
        el[(long)blockIdx.x*N_NODES + grow] = led[t];
        er[(long)blockIdx.x*N_NODES + grow] = ler[t];
      }
    }
  }
}

// Layer-1 agg: grid = N_NODES, 1 wave; thread t owns cols 8t..8t+7 (uint4 =
// 16B/lane, full 512-col row per wave), head = t>>3.
__global__ __launch_bounds__(64) void agg1_k(const unsigned short* fb, const float* el,
                       const float* er, const int* cnt, const int* bucket, unsigned short* x){
  int n = blockIdx.x;
  int t = threadIdx.x;
  long off = (long)n*CAP;
  int deg = cnt[n]; if(deg>CAP) deg=CAP;
  __shared__ int sidx[CAP];
  __shared__ float wl[CAP][8];   // [edge][head]: 8 consecutive floats -> 8 banks
  __shared__ float sinv[8];
  for(int i=t;i<deg;i+=64) sidx[i]=bucket[off+i];
  __syncthreads();
  float4 erA = *(const float4*)(er + (long)n*HEADS);
  float4 erB = *(const float4*)(er + (long)n*HEADS + 4);
  float pw[8];
  #pragma unroll
  for(int h=0;h<8;h++) pw[h]=0.f;
  for(int i=t;i<deg;i+=64){
    int s = sidx[i];
    float4 eA = *(const float4*)(el + (long)s*HEADS);
    float4 eB = *(const float4*)(el + (long)s*HEADS + 4);
    float ee[8] = {eA.x+erA.x, eA.y+erA.y, eA.z+erA.z, eA.w+erA.w,
                   eB.x+erB.x, eB.y+erB.y, eB.z+erB.z, eB.w+erB.w};
    #pragma unroll
    for(int h=0;h<8;h++){
      float e = ee[h]; e = e>0.f ? e : NEG*e;
      float w = __expf(e);
      wl[i][h]=w;
      pw[h]+=w;
    }
  }
  #pragma unroll
  for(int h=0;h<8;h++){
    #pragma unroll
    for(int o=32;o>0;o>>=1) pw[h] += __shfl_xor(pw[h],o);
  }
  if(t==0){
    #pragma unroll
    for(int h=0;h<8;h++) sinv[h] = pw[h]>0.f ? 1.f/pw[h] : 0.f;
  }
  __syncthreads();
  int hl = t>>3;
  float inv = sinv[hl];
  int c0 = 8*t;
  float a0=0.f,a1=0.f,a2=0.f,a3=0.f,a4=0.f,a5=0.f,a6=0.f,a7=0.f;
  #pragma unroll 4
  for(int i=0;i<deg;i++){
    int s = sidx[i];
    float w = wl[i][hl];
    uint4 u = *(const uint4*)(fb + (long)s*HID + c0);
    a0 += w*bflo(u.x); a1 += w*bfhi(u.x);
    a2 += w*bflo(u.y); a3 += w*bfhi(u.y);
    a4 += w*bflo(u.z); a5 += w*bfhi(u.z);
    a6 += w*bflo(u.w); a7 += w*bfhi(u.w);
  }
  a0*=inv; a1*=inv; a2*=inv; a3*=inv; a4*=inv; a5*=inv; a6*=inv; a7*=inv;
  a0 = a0>0.f ? a0 : __expf(a0)-1.f;   // ELU
  a1 = a1>0.f ? a1 : __expf(a1)-1.f;
  a2 = a2>0.f ? a2 : __expf(a2)-1.f;
  a3 = a3>0.f ? a3 : __expf(a3)-1.f;
  a4 = a4>0.f ? a4 : __expf(a4)-1.f;
  a5 = a5>0.f ? a5 : __expf(a5)-1.f;
  a6 = a6>0.f ? a6 : __expf(a6)-1.f;
  a7 = a7>0.f ? a7 : __expf(a7)-1.f;
  uint4 o4;
  o4.x = (unsigned int)f2bf(a0) | ((unsigned int)f2bf(a1)<<16);
  o4.y = (unsigned int)f2bf(a2) | ((unsigned int)f2bf(a3)<<16);
  o4.z = (unsigned int)f2bf(a4) | ((unsigned int)f2bf(a5)<<16);
  o4.w = (unsigned int)f2bf(a6) | ((unsigned int)f2bf(a7)<<16);
  *(uint4*)(x + (long)n*HID + c0) = o4;
}

// Layer-2 agg: grid = N_NODES, 1 wave; thread t owns cols 4t..4t+3.
// el/er come as 4 per-tile partials (elp[c*N_NODES+s]).
__global__ __launch_bounds__(64) void agg2_k(const unsigned short* fb, const float* elp,
                       const float* erp, const int* cnt, const int* bucket, void* out,
                       const int* modep){
  int md = *modep;
  int n = blockIdx.x, t = threadIdx.x;
  long off = (long)n*CAP;
  int deg = cnt[n]; if(deg>CAP) deg=CAP;
  __shared__ int sidx[CAP];
  __shared__ float wl[CAP];
  for(int i=t;i<deg;i+=64) sidx[i]=bucket[off+i];
  __syncthreads();
  float ern = erp[n] + erp[N_NODES+n] + erp[2*N_NODES+n] + erp[3*N_NODES+n];
  float pw = 0.f;
  for(int i=t;i<deg;i+=64){
    int s = sidx[i];
    float e = elp[s] + elp[N_NODES+s] + elp[2*N_NODES+s] + elp[3*N_NODES+s] + ern;
    e = e>0.f ? e : NEG*e;
    float w = __expf(e);
    wl[i]=w;
    pw += w;
  }
  #pragma unroll
  for(int o=32;o>0;o>>=1) pw += __shfl_xor(pw,o);
  float inv = pw>0.f ? 1.f/pw : 0.f;
  __syncthreads();
  int c0 = 4*t;
  float a0=0.f,a1=0.f,a2=0.f,a3=0.f;
  #pragma unroll 4
  for(int i=0;i<deg;i++){
    int s = sidx[i];
    float w = wl[i];
    uint2 u = *(const uint2*)(fb + (long)s*OUT_DIM + c0);
    a0 += w*bflo(u.x); a1 += w*bfhi(u.x);
    a2 += w*bflo(u.y); a3 += w*bfhi(u.y);
  }
  a0*=inv; a1*=inv; a2*=inv; a3*=inv;
  long oi = (long)n*OUT_DIM + c0;
  if(md){
    float4 fo; fo.x=a0; fo.y=a1; fo.z=a2; fo.w=a3;
    *(float4*)((float*)out + oi) = fo;
  } else {
    uint2 o2;
    o2.x = (unsigned int)f2bf(a0) | ((unsigned int)f2bf(a1)<<16);
    o2.y = (unsigned int)f2bf(a2) | ((unsigned int)f2bf(a3)<<16);
    *(uint2*)((unsigned short*)out + oi) = o2;
  }
}

extern "C" void kernel_launch(void* const* d_in, const int* in_sizes, int n_in,
                              void* d_out, int out_size, void* d_ws, size_t ws_size,
                              hipStream_t stream){
  (void)n_in; (void)out_size; (void)ws_size;
  const void* h_in = d_in[0];
  const void* W1   = d_in[1];
  const void* al1  = d_in[2];
  const void* ar1  = d_in[3];
  const void* W2   = d_in[4];
  const void* al2  = d_in[5];
  const void* ar2  = d_in[6];
  const int* src = (const int*)d_in[7];
  const int* dst = (const int*)d_in[8];
  int E = in_sizes[7];

  char* ws = (char*)d_ws;
  size_t o = 0;
  auto alloc = [&](size_t b){ size_t c=o; o += (b+255)&~(size_t)255; return c; };
  unsigned short* f1b  = (unsigned short*)(ws + alloc((size_t)N_NODES*HID*2));
  unsigned short* f2b  = (unsigned short*)(ws + alloc((size_t)N_NODES*OUT_DIM*2));
  unsigned short* xbuf = (unsigned short*)(ws + alloc((size_t)N_NODES*HID*2));
  unsigned short* wt1  = (unsigned short*)(ws + alloc((size_t)IN_DIM*HID*2));
  unsigned short* wt2  = (unsigned short*)(ws + alloc((size_t)HID*OUT_DIM*2));
  float* el1   = (float*)(ws + alloc((size_t)N_NODES*HEADS*4));
  float* er1   = (float*)(ws + alloc((size_t)N_NODES*HEADS*4));
  float* el2p  = (float*)(ws + alloc((size_t)4*N_NODES*4));
  float* er2p  = (float*)(ws + alloc((size_t)4*N_NODES*4));
  int* cnt     = (int*)(ws + alloc((size_t)N_NODES*4));
  int* bucket  = (int*)(ws + alloc((size_t)N_NODES*CAP*4));
  int* modep   = (int*)(ws + alloc(256));

  detect_zero_k<<<1+(N_NODES+255)/256,256,0,stream>>>(
      (const unsigned short*)W1, modep, cnt);
  prep2_k<<<WPREP_BLOCKS+(E+255)/256,256,0,stream>>>(
      W1, W2, wt1, wt2, modep, src, dst, cnt, bucket, E);

  // layer 1 (gemm + fused dots1, direct store)
  gemm_k<<<dim3(HID/64,(N_NODES+63)/64),256,0,stream>>>(
      h_in, wt1, f1b, N_NODES, HID, IN_DIM, 1, modep, al1, ar1, el1, er1, 1);
  agg1_k<<<N_NODES,64,0,stream>>>(f1b, el1, er1, cnt, bucket, xbuf);

  // layer 2 (gemm + fused dots2, per-tile partial store)
  gemm_k<<<dim3(OUT_DIM/64,(N_NODES+63)/64),256,0,stream>>>(
      xbuf, wt2, f2b, N_NODES, OUT_DIM, HID, 0, modep, al2, ar2, el2p, er2p, 2);
  agg2_k<<<N_NODES,64,0,stream>>>(f2b, el2p, er2p, cnt, bucket, d_out, modep);
}

// Round 11
// 184.865 us; speedup vs baseline: 1.0540x; 1.0540x over previous
//
#include <hip/hip_runtime.h>
#include <hip/hip_bf16.h>

#define N_NODES 10000
#define IN_DIM 256
#define HID 512      // HEADS*HIDDEN
#define HEADS 8
#define OUT_DIM 256
#define NEG 0.2f
#define CAP 128      // bucket capacity per node (actual max deg ~57 incl self-loop)
#define WPREP_BLOCKS (((IN_DIM*HID)+(HID*OUT_DIM))/256)   // 1024

typedef __hip_bfloat16 bf16;
typedef __attribute__((ext_vector_type(8))) short short8;
typedef __attribute__((ext_vector_type(4))) float f32x4;

__device__ __forceinline__ float ldm(const void* p, long i, int mode){
  if(mode) return ((const float*)p)[i];
  return __bfloat162float(((const bf16*)p)[i]);
}
__device__ __forceinline__ unsigned short f2bf(float f){
  bf16 b = __float2bfloat16(f);
  return *(unsigned short*)&b;
}
__device__ __forceinline__ float bflo(unsigned int u){ return __uint_as_float(u<<16); }
__device__ __forceinline__ float bfhi(unsigned int u){ return __uint_as_float(u&0xffff0000u); }

// block 0: sniff bf16-vs-f32. blocks 1..: zero cnt + el2/er2 (el1/er1 are
// direct-stored by gemm1's epilogue — no zeroing needed).
__global__ void detect_zero_k(const unsigned short* w1raw, int* mode, int* cnt,
                              float* el2, float* er2){
  int t = threadIdx.x;
  if(blockIdx.x==0){
    __shared__ int sbad;
    if(t==0) sbad=0;
    __syncthreads();
    int bad=0;
    for(int i=t;i<512;i+=256){
      unsigned int u = ((unsigned int)w1raw[i])<<16;
      float f = __uint_as_float(u);
      if(!(f==f) || fabsf(f) > 100.0f) bad++;
    }
    #pragma unroll
    for(int o=32;o>0;o>>=1) bad += __shfl_down(bad,o);
    if((t&63)==0) atomicAdd(&sbad, bad);
    __syncthreads();
    if(t==0) *mode = (sbad>10) ? 1 : 0;
  } else {
    int i = (blockIdx.x-1)*256 + t;
    if(i<N_NODES){ cnt[i]=0; el2[i]=0.f; er2[i]=0.f; }
  }
}

// blocks [0,WPREP_BLOCKS): weight transpose W1->wt1[HID][K1], W2->wt2[OUT][K2].
// blocks [WPREP_BLOCKS,..): bucketed CSR scatter (cnt pre-zeroed).
__global__ void prep2_k(const void* W1, const void* W2, unsigned short* wt1,
                        unsigned short* wt2, const int* modep,
                        const int* src, const int* dst, int* cnt, int* bucket, int E){
  int b = blockIdx.x, t = threadIdx.x;
  if(b < WPREP_BLOCKS){
    int md = *modep;
    long i = (long)b*256 + t;
    const long n1 = (long)IN_DIM*HID;
    if(i < n1){
      int k = (int)(i/HID), n = (int)(i%HID);
      unsigned short v = md ? f2bf(((const float*)W1)[i]) : ((const unsigned short*)W1)[i];
      wt1[(long)n*IN_DIM + k] = v;
    } else {
      long j = i - n1;
      int k = (int)(j/OUT_DIM), n = (int)(j%OUT_DIM);
      unsigned short v = md ? f2bf(((const float*)W2)[j]) : ((const unsigned short*)W2)[j];
      wt2[(long)n*HID + k] = v;
    }
  } else {
    int e = (b-WPREP_BLOCKS)*256 + t;
    if(e<E){
      int d = dst[e];
      int pos = atomicAdd(&cnt[d], 1);
      if(pos < CAP) bucket[(long)d*CAP + pos] = src[e];
    }
  }
}

// C[M,N]bf16 = A[M,K] @ Bt[N,K]^T with fused attention-dot epilogue.
// 64x64 tile, BK=32, 4 waves (each 32x32 = 2x2 16x16x32 frags).
// dmode==1: el/er direct-STORE (stride 8, head=bx is sole contributor).
// dmode==2: el/er atomicAdd (stride 1, 4 col-tiles contribute).
__global__ __launch_bounds__(256) void gemm_k(const void* A, const unsigned short* Bt,
                                              unsigned short* C, int M, int N, int K,
                                              int asel, const int* modep,
                                              const void* al, const void* ar,
                                              float* el, float* er, int dmode){
  int md = *modep;
  int am = asel ? md : 0;   // 1 -> A is f32
  __shared__ short As[64*40];
  __shared__ short Bs[64*40];
  __shared__ float led[64], ler[64];
  int t = threadIdx.x;
  int lane = t & 63, wave = t >> 6;
  int l15 = lane & 15, quad = lane >> 4;
  int wm = (wave>>1)*32, wn = (wave&1)*32;
  int mbase = blockIdx.y*64, nbase = blockIdx.x*64;

  f32x4 acc[2][2];
  #pragma unroll
  for(int i=0;i<2;i++)
    #pragma unroll
    for(int j=0;j<2;j++) acc[i][j] = (f32x4){0.f,0.f,0.f,0.f};

  int row = t>>2, kk = (t&3)*8;
  long arow = (long)(mbase+row)*K, brow = (long)(nbase+row)*K;
  bool av = (mbase+row) < M;
  const unsigned short* Ab = (const unsigned short*)A;
  const float* Af = (const float*)A;

  for(int k0=0;k0<K;k0+=32){
    short8 a = (short8){0,0,0,0,0,0,0,0};
    if(am){
      if(av){
        float4 x = *(const float4*)(Af + arow + k0 + kk);
        float4 y = *(const float4*)(Af + arow + k0 + kk + 4);
        a[0]=f2bf(x.x); a[1]=f2bf(x.y); a[2]=f2bf(x.z); a[3]=f2bf(x.w);
        a[4]=f2bf(y.x); a[5]=f2bf(y.y); a[6]=f2bf(y.z); a[7]=f2bf(y.w);
      }
    } else {
      if(av) a = *(const short8*)(Ab + arow + k0 + kk);
    }
    short8 b = *(const short8*)(Bt + brow + k0 + kk);
    __syncthreads();
    *(short8*)(As + row*40 + kk) = a;
    *(short8*)(Bs + row*40 + kk) = b;
    __syncthreads();
    short8 af[2], bfr[2];
    #pragma unroll
    for(int mi=0;mi<2;mi++) af[mi]  = *(short8*)(As + (wm + mi*16 + l15)*40 + quad*8);
    #pragma unroll
    for(int ni=0;ni<2;ni++) bfr[ni] = *(short8*)(Bs + (wn + ni*16 + l15)*40 + quad*8);
    #pragma unroll
    for(int mi=0;mi<2;mi++)
      #pragma unroll
      for(int ni=0;ni<2;ni++)
        acc[mi][ni] = __builtin_amdgcn_mfma_f32_16x16x32_bf16(af[mi], bfr[ni], acc[mi][ni], 0,0,0);
  }

  // C store (bf16)
  #pragma unroll
  for(int mi=0;mi<2;mi++){
    #pragma unroll
    for(int ni=0;ni<2;ni++){
      int grow0 = mbase + wm + mi*16 + quad*4;
      int gcol  = nbase + wn + ni*16 + l15;
      #pragma unroll
      for(int r=0;r<4;r++){
        int grow = grow0 + r;
        if(grow < M) C[(long)grow*N + gcol] = f2bf(acc[mi][ni][r]);
      }
    }
  }

  // fused dots epilogue: partial el/er for this block's 64 rows
  float avv[2], rvv[2];
  #pragma unroll
  for(int ni=0;ni<2;ni++){
    int gc = nbase + wn + ni*16 + l15;
    avv[ni] = ldm(al, gc, md);
    rvv[ni] = ldm(ar, gc, md);
  }
  __syncthreads();
  if(t<64){ led[t]=0.f; ler[t]=0.f; }
  __syncthreads();
  #pragma unroll
  for(int mi=0;mi<2;mi++){
    #pragma unroll
    for(int r=0;r<4;r++){
      float pl = acc[mi][0][r]*avv[0] + acc[mi][1][r]*avv[1];
      float pr = acc[mi][0][r]*rvv[0] + acc[mi][1][r]*rvv[1];
      #pragma unroll
      for(int o=1;o<16;o<<=1){ pl += __shfl_xor(pl,o); pr += __shfl_xor(pr,o); }
      if(l15==0){
        int lr = wm + mi*16 + quad*4 + r;
        atomicAdd(&led[lr], pl);
        atomicAdd(&ler[lr], pr);
      }
    }
  }
  __syncthreads();
  if(t<64){
    int grow = mbase + t;
    if(grow < M){
      if(dmode==1){
        el[(long)grow*HEADS + blockIdx.x] = led[t];
        er[(long)grow*HEADS + blockIdx.x] = ler[t];
      } else {
        atomicAdd(&el[grow], led[t]);
        atomicAdd(&er[grow], ler[t]);
      }
    }
  }
}

// Layer-1 agg, half-sliced: grid = 2*N_NODES (half ch = b/N slowest-varying).
// 1 wave/block; thread t owns cols ch*256 + 4t..4t+3 (head ch*4 + (t>>4)).
__global__ __launch_bounds__(64) void agg1_k(const unsigned short* fb, const float* el,
                       const float* er, const int* cnt, const int* bucket, unsigned short* x){
  int b = blockIdx.x;
  int ch = b / N_NODES;
  int n  = b - ch*N_NODES;
  int t = threadIdx.x;
  long off = (long)n*CAP;
  int deg = cnt[n]; if(deg>CAP) deg=CAP;
  __shared__ int sidx[CAP];
  __shared__ float wl[4][CAP];
  for(int i=t;i<deg;i+=64) sidx[i]=bucket[off+i];
  __syncthreads();
  int h0 = ch*4;
  float4 erv = *(const float4*)(er + (long)n*HEADS + h0);   // 16B aligned
  float pw0=0.f, pw1=0.f, pw2=0.f, pw3=0.f;
  for(int i=t;i<deg;i+=64){
    int s = sidx[i];
    float4 ev = *(const float4*)(el + (long)s*HEADS + h0);
    float e0 = ev.x + erv.x; e0 = e0>0.f?e0:NEG*e0;
    float e1 = ev.y + erv.y; e1 = e1>0.f?e1:NEG*e1;
    float e2 = ev.z + erv.z; e2 = e2>0.f?e2:NEG*e2;
    float e3 = ev.w + erv.w; e3 = e3>0.f?e3:NEG*e3;
    float wa = __expf(e0), wb = __expf(e1), wc = __expf(e2), wd = __expf(e3);
    wl[0][i]=wa; wl[1][i]=wb; wl[2][i]=wc; wl[3][i]=wd;
    pw0+=wa; pw1+=wb; pw2+=wc; pw3+=wd;
  }
  #pragma unroll
  for(int o=32;o>0;o>>=1){
    pw0 += __shfl_xor(pw0,o); pw1 += __shfl_xor(pw1,o);
    pw2 += __shfl_xor(pw2,o); pw3 += __shfl_xor(pw3,o);
  }
  float invs[4];
  invs[0] = pw0>0.f?1.f/pw0:0.f; invs[1] = pw1>0.f?1.f/pw1:0.f;
  invs[2] = pw2>0.f?1.f/pw2:0.f; invs[3] = pw3>0.f?1.f/pw3:0.f;
  __syncthreads();
  int hl = t>>4;                 // local head 0..3
  int c0 = ch*256 + 4*t;
  const float* wsel = wl[hl];
  float inv = invs[hl];
  float a0=0.f,a1=0.f,a2=0.f,a3=0.f;
  #pragma unroll 4
  for(int i=0;i<deg;i++){
    int s = sidx[i];
    float w = wsel[i];
    uint2 u = *(const uint2*)(fb + (long)s*HID + c0);
    a0 += w*bflo(u.x); a1 += w*bfhi(u.x);
    a2 += w*bflo(u.y); a3 += w*bfhi(u.y);
  }
  a0*=inv; a1*=inv; a2*=inv; a3*=inv;
  a0 = a0>0.f ? a0 : __expf(a0)-1.f;   // ELU
  a1 = a1>0.f ? a1 : __expf(a1)-1.f;
  a2 = a2>0.f ? a2 : __expf(a2)-1.f;
  a3 = a3>0.f ? a3 : __expf(a3)-1.f;
  uint2 o2;
  o2.x = (unsigned int)f2bf(a0) | ((unsigned int)f2bf(a1)<<16);
  o2.y = (unsigned int)f2bf(a2) | ((unsigned int)f2bf(a3)<<16);
  *(uint2*)(x + (long)n*HID + c0) = o2;
}

// Layer-2 agg: grid = N_NODES, 1 wave; thread t owns cols 4t..4t+3 (full row).
__global__ __launch_bounds__(64) void agg2_k(const unsigned short* fb, const float* el,
                       const float* er, const int* cnt, const int* bucket, void* out,
                       const int* modep){
  int md = *modep;
  int n = blockIdx.x, t = threadIdx.x;
  long off = (long)n*CAP;
  int deg = cnt[n]; if(deg>CAP) deg=CAP;
  __shared__ int sidx[CAP];
  __shared__ float wl[CAP];
  for(int i=t;i<deg;i+=64) sidx[i]=bucket[off+i];
  __syncthreads();
  float ern = er[n];
  float pw = 0.f;
  for(int i=t;i<deg;i+=64){
    int s = sidx[i];
    float e = el[s]+ern; e = e>0.f ? e : NEG*e;
    float w = __expf(e);
    wl[i]=w;
    pw += w;
  }
  #pragma unroll
  for(int o=32;o>0;o>>=1) pw += __shfl_xor(pw,o);
  float inv = pw>0.f ? 1.f/pw : 0.f;
  __syncthreads();
  int c0 = 4*t;
  float a0=0.f,a1=0.f,a2=0.f,a3=0.f;
  #pragma unroll 4
  for(int i=0;i<deg;i++){
    int s = sidx[i];
    float w = wl[i];
    uint2 u = *(const uint2*)(fb + (long)s*OUT_DIM + c0);
    a0 += w*bflo(u.x); a1 += w*bfhi(u.x);
    a2 += w*bflo(u.y); a3 += w*bfhi(u.y);
  }
  a0*=inv; a1*=inv; a2*=inv; a3*=inv;
  long oi = (long)n*OUT_DIM + c0;
  if(md){
    float4 fo; fo.x=a0; fo.y=a1; fo.z=a2; fo.w=a3;
    *(float4*)((float*)out + oi) = fo;
  } else {
    uint2 o2;
    o2.x = (unsigned int)f2bf(a0) | ((unsigned int)f2bf(a1)<<16);
    o2.y = (unsigned int)f2bf(a2) | ((unsigned int)f2bf(a3)<<16);
    *(uint2*)((unsigned short*)out + oi) = o2;
  }
}

extern "C" void kernel_launch(void* const* d_in, const int* in_sizes, int n_in,
                              void* d_out, int out_size, void* d_ws, size_t ws_size,
                              hipStream_t stream){
  (void)n_in; (void)out_size; (void)ws_size;
  const void* h_in = d_in[0];
  const void* W1   = d_in[1];
  const void* al1  = d_in[2];
  const void* ar1  = d_in[3];
  const void* W2   = d_in[4];
  const void* al2  = d_in[5];
  const void* ar2  = d_in[6];
  const int* src = (const int*)d_in[7];
  const int* dst = (const int*)d_in[8];
  int E = in_sizes[7];

  char* ws = (char*)d_ws;
  size_t o = 0;
  auto alloc = [&](size_t b){ size_t c=o; o += (b+255)&~(size_t)255; return c; };
  unsigned short* f1b  = (unsigned short*)(ws + alloc((size_t)N_NODES*HID*2));
  unsigned short* f2b  = (unsigned short*)(ws + alloc((size_t)N_NODES*OUT_DIM*2));
  unsigned short* xbuf = (unsigned short*)(ws + alloc((size_t)N_NODES*HID*2));
  unsigned short* wt1  = (unsigned short*)(ws + alloc((size_t)IN_DIM*HID*2));
  unsigned short* wt2  = (unsigned short*)(ws + alloc((size_t)HID*OUT_DIM*2));
  float* el1   = (float*)(ws + alloc((size_t)N_NODES*HEADS*4));
  float* er1   = (float*)(ws + alloc((size_t)N_NODES*HEADS*4));
  float* el2   = (float*)(ws + alloc((size_t)N_NODES*4));
  float* er2   = (float*)(ws + alloc((size_t)N_NODES*4));
  int* cnt     = (int*)(ws + alloc((size_t)N_NODES*4));
  int* bucket  = (int*)(ws + alloc((size_t)N_NODES*CAP*4));
  int* modep   = (int*)(ws + alloc(256));

  detect_zero_k<<<1+(N_NODES+255)/256,256,0,stream>>>(
      (const unsigned short*)W1, modep, cnt, el2, er2);
  prep2_k<<<WPREP_BLOCKS+(E+255)/256,256,0,stream>>>(
      W1, W2, wt1, wt2, modep, src, dst, cnt, bucket, E);

  // layer 1 (gemm + fused dots1, direct store)
  gemm_k<<<dim3(HID/64,(N_NODES+63)/64),256,0,stream>>>(
      h_in, wt1, f1b, N_NODES, HID, IN_DIM, 1, modep, al1, ar1, el1, er1, 1);
  agg1_k<<<2*N_NODES,64,0,stream>>>(f1b, el1, er1, cnt, bucket, xbuf);

  // layer 2 (gemm + fused dots2, atomic)
  gemm_k<<<dim3(OUT_DIM/64,(N_NODES+63)/64),256,0,stream>>>(
      xbuf, wt2, f2b, N_NODES, OUT_DIM, HID, 0, modep, al2, ar2, el2, er2, 2);
  agg2_k<<<N_NODES,64,0,stream>>>(f2b, el2, er2, cnt, bucket, d_out, modep);
}